// Round 1
// baseline (886.463 us; speedup 1.0000x reference)
//
#include <hip/hip_runtime.h>
#include <hip/hip_bf16.h>

// GraphSAGE: 4x (mean-agg SAGEConv + ReLU) -> mean pool -> linear classifier
// N=50000 nodes, E=800000 edges, all hidden dims 128, out 64. fp32 throughout.

__global__ void k_deg(const int* __restrict__ tgt, int* __restrict__ deg, int E) {
  int e = blockIdx.x * blockDim.x + threadIdx.x;
  if (e < E) atomicAdd(&deg[tgt[e]], 1);
}

__global__ __launch_bounds__(1024) void k_scan(const int* __restrict__ deg,
                                               int* __restrict__ row_start,
                                               float* __restrict__ inv_deg, int n) {
  __shared__ int ssum[1024];
  int tid = threadIdx.x;
  int per = (n + 1023) >> 10;
  int beg = tid * per;
  int end = min(beg + per, n);
  if (end < beg) end = beg;
  int s = 0;
  for (int i = beg; i < end; ++i) s += deg[i];
  ssum[tid] = s;
  __syncthreads();
  // Hillis-Steele inclusive scan over 1024 block sums
  for (int off = 1; off < 1024; off <<= 1) {
    int t = (tid >= off) ? ssum[tid - off] : 0;
    __syncthreads();
    ssum[tid] += t;
    __syncthreads();
  }
  int run = ssum[tid] - s;  // exclusive prefix for this chunk
  for (int i = beg; i < end; ++i) {
    int d = deg[i];
    row_start[i] = run;
    run += d;
    inv_deg[i] = 1.0f / fmaxf((float)d, 1.0f);
  }
  if (tid == 1023) row_start[n] = ssum[1023];
}

__global__ void k_scatter(const int* __restrict__ src, const int* __restrict__ tgt,
                          int* __restrict__ cursor, int* __restrict__ csr_src, int E) {
  int e = blockIdx.x * blockDim.x + threadIdx.x;
  if (e < E) {
    int t = tgt[e];
    int pos = atomicAdd(&cursor[t], 1);
    csr_src[pos] = src[e];
  }
}

// One wave (64 lanes) per node; each lane owns 2 of 128 dims (float2 = 8B/lane,
// so one edge's row read is a single coalesced 512B transaction).
__global__ __launch_bounds__(256) void k_agg(
    const float* __restrict__ h, const int* __restrict__ csr_src,
    const int* __restrict__ row_start, const float* __restrict__ inv_deg,
    float* __restrict__ agg, int n_nodes) {
  int gw = (blockIdx.x * 256 + (int)threadIdx.x) >> 6;
  int lane = threadIdx.x & 63;
  if (gw >= n_nodes) return;
  int beg = row_start[gw];
  int end = row_start[gw + 1];
  float a0 = 0.f, a1 = 0.f;
  for (int e = beg; e < end; ++e) {
    int s = csr_src[e];
    float2 v = *(const float2*)(h + (size_t)s * 128 + lane * 2);
    a0 += v.x;
    a1 += v.y;
  }
  float w = inv_deg[gw];
  float2 r;
  r.x = a0 * w;
  r.y = a1 * w;
  *(float2*)(agg + (size_t)gw * 128 + lane * 2) = r;
}

// out[n][j] = relu( h[n]@Ws + agg[n]@Wn + b ) — K=256 fused GEMM.
// BM=64 nodes x BN=128 cols per block, 256 threads, 8x4 register tile each.
__global__ __launch_bounds__(256) void k_linear(
    const float* __restrict__ h, const float* __restrict__ agg,
    const float* __restrict__ Ws, const float* __restrict__ Wn,
    const float* __restrict__ bias, float* __restrict__ out, int n_nodes) {
  __shared__ float As[32][68];   // stride 68: 16B-aligned rows + bank rotation
  __shared__ float Bs[32][128];
  int tid = threadIdx.x;
  int node0 = blockIdx.x * 64;
  int m = tid & 63;
  int q = tid >> 6;   // 0..3 (A staging: which 8-k chunk)
  int jq = tid & 31;  // j0 = jq*4
  int mq = tid >> 5;  // 0..7, m0 = mq*8
  float acc[8][4];
#pragma unroll
  for (int i = 0; i < 8; ++i)
#pragma unroll
    for (int j = 0; j < 4; ++j) acc[i][j] = 0.f;

  int node_m = node0 + m;
  bool mvalid = node_m < n_nodes;

  for (int kt = 0; kt < 8; ++kt) {
    const float* A = (kt < 4) ? h : agg;
    const float* W = (kt < 4) ? Ws : Wn;
    int kbase = (kt & 3) * 32;
    // stage A (transposed): As[kk][m] = A[node0+m][kbase+kk]
    float4 a0 = make_float4(0.f, 0.f, 0.f, 0.f), a1 = a0;
    if (mvalid) {
      const float* p = A + (size_t)node_m * 128 + kbase + q * 8;
      a0 = *(const float4*)p;
      a1 = *(const float4*)(p + 4);
    }
    As[q * 8 + 0][m] = a0.x;
    As[q * 8 + 1][m] = a0.y;
    As[q * 8 + 2][m] = a0.z;
    As[q * 8 + 3][m] = a0.w;
    As[q * 8 + 4][m] = a1.x;
    As[q * 8 + 5][m] = a1.y;
    As[q * 8 + 6][m] = a1.z;
    As[q * 8 + 7][m] = a1.w;
    // stage B: Bs[kk][j] = W[kbase+kk][j]
    {
      int kk = tid >> 3;
      int jb = (tid & 7) * 16;
      const float* p = W + (size_t)(kbase + kk) * 128 + jb;
      float4 b0 = *(const float4*)p;
      float4 b1 = *(const float4*)(p + 4);
      float4 b2 = *(const float4*)(p + 8);
      float4 b3 = *(const float4*)(p + 12);
      *(float4*)&Bs[kk][jb] = b0;
      *(float4*)&Bs[kk][jb + 4] = b1;
      *(float4*)&Bs[kk][jb + 8] = b2;
      *(float4*)&Bs[kk][jb + 12] = b3;
    }
    __syncthreads();
#pragma unroll
    for (int kk = 0; kk < 32; ++kk) {
      float4 av0 = *(const float4*)&As[kk][mq * 8];
      float4 av1 = *(const float4*)&As[kk][mq * 8 + 4];
      float4 bv = *(const float4*)&Bs[kk][jq * 4];
      float a[8] = {av0.x, av0.y, av0.z, av0.w, av1.x, av1.y, av1.z, av1.w};
      float b[4] = {bv.x, bv.y, bv.z, bv.w};
#pragma unroll
      for (int i = 0; i < 8; ++i)
#pragma unroll
        for (int j = 0; j < 4; ++j) acc[i][j] += a[i] * b[j];
    }
    __syncthreads();
  }
  float bj[4];
#pragma unroll
  for (int j = 0; j < 4; ++j) bj[j] = bias[jq * 4 + j];
#pragma unroll
  for (int i = 0; i < 8; ++i) {
    int n = node0 + mq * 8 + i;
    if (n < n_nodes) {
      float4 v;
      v.x = fmaxf(acc[i][0] + bj[0], 0.f);
      v.y = fmaxf(acc[i][1] + bj[1], 0.f);
      v.z = fmaxf(acc[i][2] + bj[2], 0.f);
      v.w = fmaxf(acc[i][3] + bj[3], 0.f);
      *(float4*)&out[(size_t)n * 128 + jq * 4] = v;
    }
  }
}

__global__ __launch_bounds__(128) void k_pool(const float* __restrict__ h,
                                              float* __restrict__ partial, int n_nodes) {
  int j = threadIdx.x;
  float acc = 0.f;
  for (int n = blockIdx.x; n < n_nodes; n += gridDim.x)
    acc += h[(size_t)n * 128 + j];
  partial[blockIdx.x * 128 + j] = acc;
}

__global__ __launch_bounds__(128) void k_final(const float* __restrict__ partial,
                                               const float* __restrict__ Wc,
                                               const float* __restrict__ bc,
                                               float* __restrict__ out, int n_nodes,
                                               int nparts) {
  __shared__ float gs[128];
  int tid = threadIdx.x;
  float g = 0.f;
  for (int b = 0; b < nparts; ++b) g += partial[b * 128 + tid];
  gs[tid] = g / (float)n_nodes;
  __syncthreads();
  if (tid < 64) {
    float o = bc[tid];
    for (int d = 0; d < 128; ++d) o += gs[d] * Wc[d * 64 + tid];
    out[tid] = o;
  }
}

extern "C" void kernel_launch(void* const* d_in, const int* in_sizes, int n_in,
                              void* d_out, int out_size, void* d_ws, size_t ws_size,
                              hipStream_t stream) {
  const float* x = (const float*)d_in[0];
  const int* ei = (const int*)d_in[1];
  const float* Ws11 = (const float*)d_in[2];
  const float* Wn11 = (const float*)d_in[3];
  const float* b11 = (const float*)d_in[4];
  const float* Ws12 = (const float*)d_in[5];
  const float* Wn12 = (const float*)d_in[6];
  const float* b12 = (const float*)d_in[7];
  const float* Ws21 = (const float*)d_in[8];
  const float* Wn21 = (const float*)d_in[9];
  const float* b21 = (const float*)d_in[10];
  const float* Ws22 = (const float*)d_in[11];
  const float* Wn22 = (const float*)d_in[12];
  const float* b22 = (const float*)d_in[13];
  const float* Wc = (const float*)d_in[14];
  const float* bc = (const float*)d_in[15];

  int N = in_sizes[0] / 128;
  int E = in_sizes[1] / 2;
  const int* src = ei;
  const int* tgt = ei + E;

  // workspace layout (fp32 words)
  float* hA = (float*)d_ws;                  // N*128
  float* hB = hA + (size_t)N * 128;          // N*128
  float* agg = hB + (size_t)N * 128;         // N*128
  float* partial = agg + (size_t)N * 128;    // 256*128
  float* inv_deg = partial + 256 * 128;      // N
  int* deg = (int*)(inv_deg + N);            // N
  int* row_start = deg + N;                  // N+1
  int* cursor = row_start + N + 1;           // N
  int* csr_src = cursor + N;                 // E

  hipMemsetAsync(deg, 0, (size_t)N * 4, stream);
  int eb = (E + 255) / 256;
  k_deg<<<eb, 256, 0, stream>>>(tgt, deg, E);
  k_scan<<<1, 1024, 0, stream>>>(deg, row_start, inv_deg, N);
  hipMemcpyAsync(cursor, row_start, (size_t)N * 4, hipMemcpyDeviceToDevice, stream);
  k_scatter<<<eb, 256, 0, stream>>>(src, tgt, cursor, csr_src, E);

  int ab = (N + 3) / 4;    // k_agg: 4 waves/block, 1 node/wave
  int lb = (N + 63) / 64;  // k_linear: 64 nodes/block

  // layer 1: x -> hA
  k_agg<<<ab, 256, 0, stream>>>(x, csr_src, row_start, inv_deg, agg, N);
  k_linear<<<lb, 256, 0, stream>>>(x, agg, Ws11, Wn11, b11, hA, N);
  // layer 2: hA -> hB
  k_agg<<<ab, 256, 0, stream>>>(hA, csr_src, row_start, inv_deg, agg, N);
  k_linear<<<lb, 256, 0, stream>>>(hA, agg, Ws12, Wn12, b12, hB, N);
  // layer 3: hB -> hA
  k_agg<<<ab, 256, 0, stream>>>(hB, csr_src, row_start, inv_deg, agg, N);
  k_linear<<<lb, 256, 0, stream>>>(hB, agg, Ws21, Wn21, b21, hA, N);
  // layer 4: hA -> hB
  k_agg<<<ab, 256, 0, stream>>>(hA, csr_src, row_start, inv_deg, agg, N);
  k_linear<<<lb, 256, 0, stream>>>(hA, agg, Ws22, Wn22, b22, hB, N);

  k_pool<<<256, 128, 0, stream>>>(hB, partial, N);
  k_final<<<1, 128, 0, stream>>>(partial, Wc, bc, (float*)d_out, N, 256);
}

// Round 2
// 782.892 us; speedup vs baseline: 1.1323x; 1.1323x over previous
//
#include <hip/hip_runtime.h>
#include <hip/hip_bf16.h>

// GraphSAGE: 4x (mean-agg SAGEConv + ReLU) -> mean pool -> linear classifier
// N=50000 nodes, E=800000 edges, all hidden dims 128, out 64. fp32 throughout.

__global__ void k_deg(const int* __restrict__ tgt, int* __restrict__ deg, int E) {
  int e = blockIdx.x * blockDim.x + threadIdx.x;
  if (e < E) atomicAdd(&deg[tgt[e]], 1);
}

// --- parallel exclusive scan over deg[0..n) -> row_start, cursor, inv_deg ---
__global__ __launch_bounds__(256) void k_scan1(const int* __restrict__ deg,
                                               int* __restrict__ partial,
                                               int* __restrict__ blocksum,
                                               float* __restrict__ inv_deg, int n) {
  __shared__ int s[256];
  int tid = threadIdx.x;
  int i = blockIdx.x * 256 + tid;
  int v = (i < n) ? deg[i] : 0;
  s[tid] = v;
  __syncthreads();
  for (int off = 1; off < 256; off <<= 1) {
    int t = (tid >= off) ? s[tid - off] : 0;
    __syncthreads();
    s[tid] += t;
    __syncthreads();
  }
  if (i < n) {
    partial[i] = s[tid] - v;  // exclusive within block
    inv_deg[i] = 1.0f / fmaxf((float)v, 1.0f);
  }
  if (tid == 255) blocksum[blockIdx.x] = s[255];
}

__global__ __launch_bounds__(256) void k_scan2(int* __restrict__ blocksum, int nb) {
  __shared__ int s[256];
  int tid = threadIdx.x;
  int v = (tid < nb) ? blocksum[tid] : 0;
  s[tid] = v;
  __syncthreads();
  for (int off = 1; off < 256; off <<= 1) {
    int t = (tid >= off) ? s[tid - off] : 0;
    __syncthreads();
    s[tid] += t;
    __syncthreads();
  }
  if (tid < nb) blocksum[tid] = s[tid] - v;  // exclusive block offsets
}

__global__ __launch_bounds__(256) void k_scan3(const int* __restrict__ partial,
                                               const int* __restrict__ blocksum,
                                               int* __restrict__ row_start,
                                               int* __restrict__ cursor, int n, int E) {
  int i = blockIdx.x * 256 + threadIdx.x;
  if (i < n) {
    int r = partial[i] + blocksum[blockIdx.x];
    row_start[i] = r;
    cursor[i] = r;
  }
  if (i == 0) row_start[n] = E;
}

__global__ void k_scatter(const int* __restrict__ src, const int* __restrict__ tgt,
                          int* __restrict__ cursor, int* __restrict__ csr_src, int E) {
  int e = blockIdx.x * blockDim.x + threadIdx.x;
  if (e < E) {
    int t = tgt[e];
    int pos = atomicAdd(&cursor[t], 1);
    csr_src[pos] = src[e];
  }
}

// One wave (64 lanes) per node; each lane owns 2 of 128 dims (float2 = 8B/lane,
// so one edge's row read is a single coalesced 512B transaction).
__global__ __launch_bounds__(256) void k_agg(
    const float* __restrict__ h, const int* __restrict__ csr_src,
    const int* __restrict__ row_start, const float* __restrict__ inv_deg,
    float* __restrict__ agg, int n_nodes) {
  int gw = (blockIdx.x * 256 + (int)threadIdx.x) >> 6;
  int lane = threadIdx.x & 63;
  if (gw >= n_nodes) return;
  int beg = row_start[gw];
  int end = row_start[gw + 1];
  float a0 = 0.f, a1 = 0.f;
  for (int e = beg; e < end; ++e) {
    int s = csr_src[e];
    float2 v = *(const float2*)(h + (size_t)s * 128 + lane * 2);
    a0 += v.x;
    a1 += v.y;
  }
  float w = inv_deg[gw];
  float2 r;
  r.x = a0 * w;
  r.y = a1 * w;
  *(float2*)(agg + (size_t)gw * 128 + lane * 2) = r;
}

// out[n][j] = relu( h[n]@Ws + agg[n]@Wn + b ) — K=256 fused GEMM.
// BM=64 nodes x BN=128 cols per block, 256 threads, 8x4 register tile each.
__global__ __launch_bounds__(256) void k_linear(
    const float* __restrict__ h, const float* __restrict__ agg,
    const float* __restrict__ Ws, const float* __restrict__ Wn,
    const float* __restrict__ bias, float* __restrict__ out, int n_nodes) {
  __shared__ float As[32][68];   // stride 68: 16B-aligned rows + bank rotation
  __shared__ float Bs[32][128];
  int tid = threadIdx.x;
  int node0 = blockIdx.x * 64;
  int m = tid & 63;
  int q = tid >> 6;   // 0..3 (A staging: which 8-k chunk)
  int jq = tid & 31;  // j0 = jq*4
  int mq = tid >> 5;  // 0..7, m0 = mq*8
  float acc[8][4];
#pragma unroll
  for (int i = 0; i < 8; ++i)
#pragma unroll
    for (int j = 0; j < 4; ++j) acc[i][j] = 0.f;

  int node_m = node0 + m;
  bool mvalid = node_m < n_nodes;

  for (int kt = 0; kt < 8; ++kt) {
    const float* A = (kt < 4) ? h : agg;
    const float* W = (kt < 4) ? Ws : Wn;
    int kbase = (kt & 3) * 32;
    // stage A (transposed): As[kk][m] = A[node0+m][kbase+kk]
    float4 a0 = make_float4(0.f, 0.f, 0.f, 0.f), a1 = a0;
    if (mvalid) {
      const float* p = A + (size_t)node_m * 128 + kbase + q * 8;
      a0 = *(const float4*)p;
      a1 = *(const float4*)(p + 4);
    }
    As[q * 8 + 0][m] = a0.x;
    As[q * 8 + 1][m] = a0.y;
    As[q * 8 + 2][m] = a0.z;
    As[q * 8 + 3][m] = a0.w;
    As[q * 8 + 4][m] = a1.x;
    As[q * 8 + 5][m] = a1.y;
    As[q * 8 + 6][m] = a1.z;
    As[q * 8 + 7][m] = a1.w;
    // stage B: Bs[kk][j] = W[kbase+kk][j]
    {
      int kk = tid >> 3;
      int jb = (tid & 7) * 16;
      const float* p = W + (size_t)(kbase + kk) * 128 + jb;
      float4 b0 = *(const float4*)p;
      float4 b1 = *(const float4*)(p + 4);
      float4 b2 = *(const float4*)(p + 8);
      float4 b3 = *(const float4*)(p + 12);
      *(float4*)&Bs[kk][jb] = b0;
      *(float4*)&Bs[kk][jb + 4] = b1;
      *(float4*)&Bs[kk][jb + 8] = b2;
      *(float4*)&Bs[kk][jb + 12] = b3;
    }
    __syncthreads();
#pragma unroll
    for (int kk = 0; kk < 32; ++kk) {
      float4 av0 = *(const float4*)&As[kk][mq * 8];
      float4 av1 = *(const float4*)&As[kk][mq * 8 + 4];
      float4 bv = *(const float4*)&Bs[kk][jq * 4];
      float a[8] = {av0.x, av0.y, av0.z, av0.w, av1.x, av1.y, av1.z, av1.w};
      float b[4] = {bv.x, bv.y, bv.z, bv.w};
#pragma unroll
      for (int i = 0; i < 8; ++i)
#pragma unroll
        for (int j = 0; j < 4; ++j) acc[i][j] += a[i] * b[j];
    }
    __syncthreads();
  }
  float bj[4];
#pragma unroll
  for (int j = 0; j < 4; ++j) bj[j] = bias[jq * 4 + j];
#pragma unroll
  for (int i = 0; i < 8; ++i) {
    int n = node0 + mq * 8 + i;
    if (n < n_nodes) {
      float4 v;
      v.x = fmaxf(acc[i][0] + bj[0], 0.f);
      v.y = fmaxf(acc[i][1] + bj[1], 0.f);
      v.z = fmaxf(acc[i][2] + bj[2], 0.f);
      v.w = fmaxf(acc[i][3] + bj[3], 0.f);
      *(float4*)&out[(size_t)n * 128 + jq * 4] = v;
    }
  }
}

__global__ __launch_bounds__(128) void k_pool(const float* __restrict__ h,
                                              float* __restrict__ partial, int n_nodes) {
  int j = threadIdx.x;
  float acc = 0.f;
  for (int n = blockIdx.x; n < n_nodes; n += gridDim.x)
    acc += h[(size_t)n * 128 + j];
  partial[blockIdx.x * 128 + j] = acc;
}

__global__ __launch_bounds__(128) void k_final(const float* __restrict__ partial,
                                               const float* __restrict__ Wc,
                                               const float* __restrict__ bc,
                                               float* __restrict__ out, int n_nodes,
                                               int nparts) {
  __shared__ float gs[128];
  int tid = threadIdx.x;
  float g = 0.f;
  for (int b = 0; b < nparts; ++b) g += partial[b * 128 + tid];
  gs[tid] = g / (float)n_nodes;
  __syncthreads();
  if (tid < 64) {
    float o = bc[tid];
    for (int d = 0; d < 128; ++d) o += gs[d] * Wc[d * 64 + tid];
    out[tid] = o;
  }
}

extern "C" void kernel_launch(void* const* d_in, const int* in_sizes, int n_in,
                              void* d_out, int out_size, void* d_ws, size_t ws_size,
                              hipStream_t stream) {
  const float* x = (const float*)d_in[0];
  const int* ei = (const int*)d_in[1];
  const float* Ws11 = (const float*)d_in[2];
  const float* Wn11 = (const float*)d_in[3];
  const float* b11 = (const float*)d_in[4];
  const float* Ws12 = (const float*)d_in[5];
  const float* Wn12 = (const float*)d_in[6];
  const float* b12 = (const float*)d_in[7];
  const float* Ws21 = (const float*)d_in[8];
  const float* Wn21 = (const float*)d_in[9];
  const float* b21 = (const float*)d_in[10];
  const float* Ws22 = (const float*)d_in[11];
  const float* Wn22 = (const float*)d_in[12];
  const float* b22 = (const float*)d_in[13];
  const float* Wc = (const float*)d_in[14];
  const float* bc = (const float*)d_in[15];

  int N = in_sizes[0] / 128;
  int E = in_sizes[1] / 2;
  const int* src = ei;
  const int* tgt = ei + E;

  // workspace layout (fp32 words)
  float* hA = (float*)d_ws;                  // N*128
  float* hB = hA + (size_t)N * 128;          // N*128
  float* agg = hB + (size_t)N * 128;         // N*128
  float* partial = agg + (size_t)N * 128;    // 256*128
  float* inv_deg = partial + 256 * 128;      // N
  int* deg = (int*)(inv_deg + N);            // N
  int* row_start = deg + N;                  // N+1
  int* cursor = row_start + N + 1;           // N
  int* csr_src = cursor + N;                 // E
  int* scanp = csr_src + E;                  // N (per-element partial)
  int* blocksum = scanp + N;                 // 256

  hipMemsetAsync(deg, 0, (size_t)N * 4, stream);
  int eb = (E + 255) / 256;
  int nb = (N + 255) / 256;
  k_deg<<<eb, 256, 0, stream>>>(tgt, deg, E);
  k_scan1<<<nb, 256, 0, stream>>>(deg, scanp, blocksum, inv_deg, N);
  k_scan2<<<1, 256, 0, stream>>>(blocksum, nb);
  k_scan3<<<nb, 256, 0, stream>>>(scanp, blocksum, row_start, cursor, N, E);
  k_scatter<<<eb, 256, 0, stream>>>(src, tgt, cursor, csr_src, E);

  int ab = (N + 3) / 4;    // k_agg: 4 waves/block, 1 node/wave
  int lb = (N + 63) / 64;  // k_linear: 64 nodes/block

  // layer 1: x -> hA
  k_agg<<<ab, 256, 0, stream>>>(x, csr_src, row_start, inv_deg, agg, N);
  k_linear<<<lb, 256, 0, stream>>>(x, agg, Ws11, Wn11, b11, hA, N);
  // layer 2: hA -> hB
  k_agg<<<ab, 256, 0, stream>>>(hA, csr_src, row_start, inv_deg, agg, N);
  k_linear<<<lb, 256, 0, stream>>>(hA, agg, Ws12, Wn12, b12, hB, N);
  // layer 3: hB -> hA
  k_agg<<<ab, 256, 0, stream>>>(hB, csr_src, row_start, inv_deg, agg, N);
  k_linear<<<lb, 256, 0, stream>>>(hB, agg, Ws21, Wn21, b21, hA, N);
  // layer 4: hA -> hB
  k_agg<<<ab, 256, 0, stream>>>(hA, csr_src, row_start, inv_deg, agg, N);
  k_linear<<<lb, 256, 0, stream>>>(hA, agg, Ws22, Wn22, b22, hB, N);

  k_pool<<<256, 128, 0, stream>>>(hB, partial, N);
  k_final<<<1, 128, 0, stream>>>(partial, Wc, bc, (float*)d_out, N, 256);
}

// Round 3
// 578.880 us; speedup vs baseline: 1.5313x; 1.3524x over previous
//
#include <hip/hip_runtime.h>
#include <hip/hip_bf16.h>
#include <hip/hip_fp16.h>

// GraphSAGE: 4x (mean-agg SAGEConv + ReLU) -> mean pool -> linear classifier
// N=50000, E=800000, dims 128->128->64. fp16 feature storage, fp32 accum,
// MFMA (16x16x32 f16) for the dual linear layers.

typedef _Float16 f16x8 __attribute__((ext_vector_type(8)));
typedef float f32x4 __attribute__((ext_vector_type(4)));

__global__ void k_deg(const int* __restrict__ tgt, int* __restrict__ deg, int E) {
  int e = blockIdx.x * blockDim.x + threadIdx.x;
  if (e < E) atomicAdd(&deg[tgt[e]], 1);
}

// --- parallel exclusive scan over deg[0..n) -> row_start, cursor, inv_deg ---
__global__ __launch_bounds__(256) void k_scan1(const int* __restrict__ deg,
                                               int* __restrict__ partial,
                                               int* __restrict__ blocksum,
                                               float* __restrict__ inv_deg, int n) {
  __shared__ int s[256];
  int tid = threadIdx.x;
  int i = blockIdx.x * 256 + tid;
  int v = (i < n) ? deg[i] : 0;
  s[tid] = v;
  __syncthreads();
  for (int off = 1; off < 256; off <<= 1) {
    int t = (tid >= off) ? s[tid - off] : 0;
    __syncthreads();
    s[tid] += t;
    __syncthreads();
  }
  if (i < n) {
    partial[i] = s[tid] - v;
    inv_deg[i] = 1.0f / fmaxf((float)v, 1.0f);
  }
  if (tid == 255) blocksum[blockIdx.x] = s[255];
}

__global__ __launch_bounds__(256) void k_scan2(int* __restrict__ blocksum, int nb) {
  __shared__ int s[256];
  int tid = threadIdx.x;
  int v = (tid < nb) ? blocksum[tid] : 0;
  s[tid] = v;
  __syncthreads();
  for (int off = 1; off < 256; off <<= 1) {
    int t = (tid >= off) ? s[tid - off] : 0;
    __syncthreads();
    s[tid] += t;
    __syncthreads();
  }
  if (tid < nb) blocksum[tid] = s[tid] - v;
}

__global__ __launch_bounds__(256) void k_scan3(const int* __restrict__ partial,
                                               const int* __restrict__ blocksum,
                                               int* __restrict__ row_start,
                                               int* __restrict__ cursor, int n, int E) {
  int i = blockIdx.x * 256 + threadIdx.x;
  if (i < n) {
    int r = partial[i] + blocksum[blockIdx.x];
    row_start[i] = r;
    cursor[i] = r;
  }
  if (i == 0) row_start[n] = E;
}

__global__ void k_scatter(const int* __restrict__ src, const int* __restrict__ tgt,
                          int* __restrict__ cursor, int* __restrict__ csr_src, int E) {
  int e = blockIdx.x * blockDim.x + threadIdx.x;
  if (e < E) {
    int t = tgt[e];
    int pos = atomicAdd(&cursor[t], 1);
    csr_src[pos] = src[e];
  }
}

// x fp32 -> fp16, 8 elements/thread
__global__ __launch_bounds__(256) void k_cvt_x(const float* __restrict__ x,
                                               __half* __restrict__ xh, int total8) {
  int i = blockIdx.x * 256 + threadIdx.x;
  if (i >= total8) return;
  const float4* p = (const float4*)(x + (size_t)i * 8);
  float4 v0 = p[0], v1 = p[1];
  f16x8 o;
  o[0] = (_Float16)v0.x; o[1] = (_Float16)v0.y; o[2] = (_Float16)v0.z; o[3] = (_Float16)v0.w;
  o[4] = (_Float16)v1.x; o[5] = (_Float16)v1.y; o[6] = (_Float16)v1.z; o[7] = (_Float16)v1.w;
  *(f16x8*)(xh + (size_t)i * 8) = o;
}

struct WPack {
  const float* s[4];
  const float* n[4];
};

// Wt[layer][n][k] (k in [0,256): k<128 -> Ws[k][n], else Wn[k-128][n]), fp16
__global__ __launch_bounds__(256) void k_prep_w(WPack p, __half* __restrict__ Wt) {
  int l = blockIdx.y;
  int i = blockIdx.x * 256 + threadIdx.x;  // [0, 32768)
  int n = i >> 8;
  int k = i & 255;
  const float* W = (k < 128) ? p.s[l] : p.n[l];
  float v = W[(size_t)(k & 127) * 128 + n];
  Wt[(size_t)l * 32768 + (size_t)n * 256 + k] = __float2half(v);
}

// One wave per node; lane owns 2 dims (half2 = 4B/lane -> 256B coalesced row).
__global__ __launch_bounds__(256) void k_agg_h(
    const __half* __restrict__ h, const int* __restrict__ csr_src,
    const int* __restrict__ row_start, const float* __restrict__ inv_deg,
    __half* __restrict__ agg, int n_nodes) {
  int gw = (blockIdx.x * 256 + (int)threadIdx.x) >> 6;
  int lane = threadIdx.x & 63;
  if (gw >= n_nodes) return;
  int beg = row_start[gw];
  int end = row_start[gw + 1];
  float a0 = 0.f, a1 = 0.f;
  int e = beg;
  for (; e + 1 < end; e += 2) {
    int s0 = csr_src[e];
    int s1 = csr_src[e + 1];
    __half2 v0 = *(const __half2*)(h + (size_t)s0 * 128 + lane * 2);
    __half2 v1 = *(const __half2*)(h + (size_t)s1 * 128 + lane * 2);
    float2 f0 = __half22float2(v0);
    float2 f1 = __half22float2(v1);
    a0 += f0.x + f1.x;
    a1 += f0.y + f1.y;
  }
  if (e < end) {
    int s0 = csr_src[e];
    float2 f0 = __half22float2(*(const __half2*)(h + (size_t)s0 * 128 + lane * 2));
    a0 += f0.x;
    a1 += f0.y;
  }
  float w = inv_deg[gw];
  __half2 r;
  r.x = __float2half(a0 * w);
  r.y = __float2half(a1 * w);
  *(__half2*)(agg + (size_t)gw * 128 + lane * 2) = r;
}

// out[m][n] = relu( h[m]@Ws + agg[m]@Wn + b ), K=256 via mfma_f32_16x16x32_f16.
// Block = 256 threads = 4 waves; wave w does rows [blk*64+w*16, +16), all 128 cols.
// A frag: row = lane&15, k = (lane>>4)*8+j (16B contiguous load from h/agg).
// B frag: col = lane&15, k = (lane>>4)*8+j -> 16B load from Wt[n][k] layout.
// D frag: col = lane&15, row = (lane>>4)*4+reg.
__global__ __launch_bounds__(256) void k_linear_mfma(
    const __half* __restrict__ h, const __half* __restrict__ agg,
    const __half* __restrict__ Wt, const float* __restrict__ bias,
    __half* __restrict__ out, int n_nodes) {
  int tid = threadIdx.x;
  int wave = tid >> 6;
  int lane = tid & 63;
  int m0 = blockIdx.x * 64 + wave * 16;
  int lr = lane & 15;
  int lg = lane >> 4;
  f32x4 acc[8];
#pragma unroll
  for (int ct = 0; ct < 8; ++ct) acc[ct] = (f32x4){0.f, 0.f, 0.f, 0.f};

  int arow = m0 + lr;
  if (arow >= n_nodes) arow = n_nodes - 1;
  const __half* hrow = h + (size_t)arow * 128;
  const __half* grow = agg + (size_t)arow * 128;

#pragma unroll
  for (int ks = 0; ks < 8; ++ks) {
    const __half* srcp = (ks < 4) ? hrow : grow;
    int koff = (ks & 3) * 32 + lg * 8;
    f16x8 a = *(const f16x8*)(srcp + koff);
    int kb = ks * 32 + lg * 8;
#pragma unroll
    for (int ct = 0; ct < 8; ++ct) {
      f16x8 b = *(const f16x8*)(Wt + (size_t)(ct * 16 + lr) * 256 + kb);
      acc[ct] = __builtin_amdgcn_mfma_f32_16x16x32_f16(a, b, acc[ct], 0, 0, 0);
    }
  }

#pragma unroll
  for (int ct = 0; ct < 8; ++ct) {
    int n_col = ct * 16 + lr;
    float bv = bias[n_col];
#pragma unroll
    for (int r = 0; r < 4; ++r) {
      int m = m0 + lg * 4 + r;
      if (m < n_nodes)
        out[(size_t)m * 128 + n_col] = __float2half(fmaxf(acc[ct][r] + bv, 0.f));
    }
  }
}

__global__ __launch_bounds__(128) void k_pool(const __half* __restrict__ h,
                                              float* __restrict__ partial, int n_nodes) {
  int j = threadIdx.x;
  float acc = 0.f;
  for (int n = blockIdx.x; n < n_nodes; n += gridDim.x)
    acc += __half2float(h[(size_t)n * 128 + j]);
  partial[blockIdx.x * 128 + j] = acc;
}

__global__ __launch_bounds__(128) void k_final(const float* __restrict__ partial,
                                               const float* __restrict__ Wc,
                                               const float* __restrict__ bc,
                                               float* __restrict__ out, int n_nodes,
                                               int nparts) {
  __shared__ float gs[128];
  int tid = threadIdx.x;
  float g = 0.f;
  for (int b = 0; b < nparts; ++b) g += partial[b * 128 + tid];
  gs[tid] = g / (float)n_nodes;
  __syncthreads();
  if (tid < 64) {
    float o = bc[tid];
    for (int d = 0; d < 128; ++d) o += gs[d] * Wc[d * 64 + tid];
    out[tid] = o;
  }
}

extern "C" void kernel_launch(void* const* d_in, const int* in_sizes, int n_in,
                              void* d_out, int out_size, void* d_ws, size_t ws_size,
                              hipStream_t stream) {
  const float* x = (const float*)d_in[0];
  const int* ei = (const int*)d_in[1];
  const float* Ws11 = (const float*)d_in[2];
  const float* Wn11 = (const float*)d_in[3];
  const float* b11 = (const float*)d_in[4];
  const float* Ws12 = (const float*)d_in[5];
  const float* Wn12 = (const float*)d_in[6];
  const float* b12 = (const float*)d_in[7];
  const float* Ws21 = (const float*)d_in[8];
  const float* Wn21 = (const float*)d_in[9];
  const float* b21 = (const float*)d_in[10];
  const float* Ws22 = (const float*)d_in[11];
  const float* Wn22 = (const float*)d_in[12];
  const float* b22 = (const float*)d_in[13];
  const float* Wc = (const float*)d_in[14];
  const float* bc = (const float*)d_in[15];

  int N = in_sizes[0] / 128;
  int E = in_sizes[1] / 2;
  const int* src = ei;
  const int* tgt = ei + E;

  // workspace layout (256B-aligned chunks)
  char* w = (char*)d_ws;
  size_t off = 0;
  auto alloc = [&](size_t bytes) {
    void* p = w + off;
    off += (bytes + 255) & ~(size_t)255;
    return p;
  };
  __half* xh = (__half*)alloc((size_t)N * 128 * 2);
  __half* hA = (__half*)alloc((size_t)N * 128 * 2);
  __half* hB = (__half*)alloc((size_t)N * 128 * 2);
  __half* aggb = (__half*)alloc((size_t)N * 128 * 2);
  __half* Wt = (__half*)alloc((size_t)4 * 32768 * 2);
  float* partial = (float*)alloc((size_t)256 * 128 * 4);
  float* inv_deg = (float*)alloc((size_t)N * 4);
  int* deg = (int*)alloc((size_t)N * 4);
  int* row_start = (int*)alloc((size_t)(N + 1) * 4);
  int* cursor = (int*)alloc((size_t)N * 4);
  int* csr_src = (int*)alloc((size_t)E * 4);
  int* scanp = (int*)alloc((size_t)N * 4);
  int* blocksum = (int*)alloc((size_t)256 * 4);

  hipMemsetAsync(deg, 0, (size_t)N * 4, stream);
  int eb = (E + 255) / 256;
  int nb = (N + 255) / 256;
  k_deg<<<eb, 256, 0, stream>>>(tgt, deg, E);
  k_scan1<<<nb, 256, 0, stream>>>(deg, scanp, blocksum, inv_deg, N);
  k_scan2<<<1, 256, 0, stream>>>(blocksum, nb);
  k_scan3<<<nb, 256, 0, stream>>>(scanp, blocksum, row_start, cursor, N, E);
  k_scatter<<<eb, 256, 0, stream>>>(src, tgt, cursor, csr_src, E);

  int total8 = N * 128 / 8;
  k_cvt_x<<<(total8 + 255) / 256, 256, 0, stream>>>(x, xh, total8);
  WPack wp;
  wp.s[0] = Ws11; wp.s[1] = Ws12; wp.s[2] = Ws21; wp.s[3] = Ws22;
  wp.n[0] = Wn11; wp.n[1] = Wn12; wp.n[2] = Wn21; wp.n[3] = Wn22;
  k_prep_w<<<dim3(128, 4), 256, 0, stream>>>(wp, Wt);

  int ab = (N + 3) / 4;     // k_agg_h: 4 waves/block, 1 node/wave
  int lb = (N + 63) / 64;   // k_linear_mfma: 64 rows/block

  // layer 1: xh -> hA
  k_agg_h<<<ab, 256, 0, stream>>>(xh, csr_src, row_start, inv_deg, aggb, N);
  k_linear_mfma<<<lb, 256, 0, stream>>>(xh, aggb, Wt + 0 * 32768, b11, hA, N);
  // layer 2: hA -> hB
  k_agg_h<<<ab, 256, 0, stream>>>(hA, csr_src, row_start, inv_deg, aggb, N);
  k_linear_mfma<<<lb, 256, 0, stream>>>(hA, aggb, Wt + 1 * 32768, b12, hB, N);
  // layer 3: hB -> hA
  k_agg_h<<<ab, 256, 0, stream>>>(hB, csr_src, row_start, inv_deg, aggb, N);
  k_linear_mfma<<<lb, 256, 0, stream>>>(hB, aggb, Wt + 2 * 32768, b21, hA, N);
  // layer 4: hA -> hB
  k_agg_h<<<ab, 256, 0, stream>>>(hA, csr_src, row_start, inv_deg, aggb, N);
  k_linear_mfma<<<lb, 256, 0, stream>>>(hA, aggb, Wt + 3 * 32768, b22, hB, N);

  k_pool<<<256, 128, 0, stream>>>(hB, partial, N);
  k_final<<<1, 128, 0, stream>>>(partial, Wc, bc, (float*)d_out, N, 256);
}

// Round 5
// 435.647 us; speedup vs baseline: 2.0348x; 1.3288x over previous
//
#include <hip/hip_runtime.h>
#include <hip/hip_bf16.h>
#include <hip/hip_fp16.h>

// GraphSAGE: 4x (mean-agg SAGEConv + ReLU) -> mean pool -> linear classifier
// N=50000, E=800000, dims 128->128->64. fp16 feature storage, fp32 accum,
// MFMA (16x16x32 f16) for the dual linear layers.

typedef _Float16 f16x8 __attribute__((ext_vector_type(8)));
typedef float f32x4 __attribute__((ext_vector_type(4)));

__global__ void k_deg(const int* __restrict__ tgt, int* __restrict__ deg, int E) {
  int e = blockIdx.x * blockDim.x + threadIdx.x;
  if (e < E) atomicAdd(&deg[tgt[e]], 1);
}

// --- parallel exclusive scan over deg[0..n) -> row_start, cursor, inv_deg ---
__global__ __launch_bounds__(256) void k_scan1(const int* __restrict__ deg,
                                               int* __restrict__ partial,
                                               int* __restrict__ blocksum,
                                               float* __restrict__ inv_deg, int n) {
  __shared__ int s[256];
  int tid = threadIdx.x;
  int i = blockIdx.x * 256 + tid;
  int v = (i < n) ? deg[i] : 0;
  s[tid] = v;
  __syncthreads();
  for (int off = 1; off < 256; off <<= 1) {
    int t = (tid >= off) ? s[tid - off] : 0;
    __syncthreads();
    s[tid] += t;
    __syncthreads();
  }
  if (i < n) {
    partial[i] = s[tid] - v;
    inv_deg[i] = 1.0f / fmaxf((float)v, 1.0f);
  }
  if (tid == 255) blocksum[blockIdx.x] = s[255];
}

__global__ __launch_bounds__(256) void k_scan2(int* __restrict__ blocksum, int nb) {
  __shared__ int s[256];
  int tid = threadIdx.x;
  int v = (tid < nb) ? blocksum[tid] : 0;
  s[tid] = v;
  __syncthreads();
  for (int off = 1; off < 256; off <<= 1) {
    int t = (tid >= off) ? s[tid - off] : 0;
    __syncthreads();
    s[tid] += t;
    __syncthreads();
  }
  if (tid < nb) blocksum[tid] = s[tid] - v;
}

__global__ __launch_bounds__(256) void k_scan3(const int* __restrict__ partial,
                                               const int* __restrict__ blocksum,
                                               int* __restrict__ row_start,
                                               int* __restrict__ cursor, int n, int E) {
  int i = blockIdx.x * 256 + threadIdx.x;
  if (i < n) {
    int r = partial[i] + blocksum[blockIdx.x];
    row_start[i] = r;
    cursor[i] = r;
  }
  if (i == 0) row_start[n] = E;
}

__global__ void k_scatter(const int* __restrict__ src, const int* __restrict__ tgt,
                          int* __restrict__ cursor, int* __restrict__ csr_src, int E) {
  int e = blockIdx.x * blockDim.x + threadIdx.x;
  if (e < E) {
    int t = tgt[e];
    int pos = atomicAdd(&cursor[t], 1);
    csr_src[pos] = src[e];
  }
}

// x fp32 -> fp16, 8 elements/thread
__global__ __launch_bounds__(256) void k_cvt_x(const float* __restrict__ x,
                                               __half* __restrict__ xh, int total8) {
  int i = blockIdx.x * 256 + threadIdx.x;
  if (i >= total8) return;
  const float4* p = (const float4*)(x + (size_t)i * 8);
  float4 v0 = p[0], v1 = p[1];
  f16x8 o;
  o[0] = (_Float16)v0.x; o[1] = (_Float16)v0.y; o[2] = (_Float16)v0.z; o[3] = (_Float16)v0.w;
  o[4] = (_Float16)v1.x; o[5] = (_Float16)v1.y; o[6] = (_Float16)v1.z; o[7] = (_Float16)v1.w;
  *(f16x8*)(xh + (size_t)i * 8) = o;
}

struct WPack {
  const float* s[4];
  const float* n[4];
};

// Wt[layer][n][k] (k in [0,256): k<128 -> Ws[k][n], else Wn[k-128][n]), fp16
__global__ __launch_bounds__(256) void k_prep_w(WPack p, __half* __restrict__ Wt) {
  int l = blockIdx.y;
  int i = blockIdx.x * 256 + threadIdx.x;  // [0, 32768)
  int n = i >> 8;
  int k = i & 255;
  const float* W = (k < 128) ? p.s[l] : p.n[l];
  float v = W[(size_t)(k & 127) * 128 + n];
  Wt[(size_t)l * 32768 + (size_t)n * 256 + k] = __float2half(v);
}

// One wave per node; lane owns 2 dims (half2 = 4B/lane -> 256B coalesced row).
// 4-edge unroll for memory-level parallelism (latency-bound gather).
__global__ __launch_bounds__(256) void k_agg_h(
    const __half* __restrict__ h, const int* __restrict__ csr_src,
    const int* __restrict__ row_start, const float* __restrict__ inv_deg,
    __half* __restrict__ agg, int n_nodes) {
  int gw = (blockIdx.x * 256 + (int)threadIdx.x) >> 6;
  int lane = threadIdx.x & 63;
  if (gw >= n_nodes) return;
  int beg = row_start[gw];
  int end = row_start[gw + 1];
  float a0 = 0.f, a1 = 0.f;
  int e = beg;
  for (; e + 3 < end; e += 4) {
    int s0 = csr_src[e];
    int s1 = csr_src[e + 1];
    int s2 = csr_src[e + 2];
    int s3 = csr_src[e + 3];
    __half2 v0 = *(const __half2*)(h + (size_t)s0 * 128 + lane * 2);
    __half2 v1 = *(const __half2*)(h + (size_t)s1 * 128 + lane * 2);
    __half2 v2 = *(const __half2*)(h + (size_t)s2 * 128 + lane * 2);
    __half2 v3 = *(const __half2*)(h + (size_t)s3 * 128 + lane * 2);
    float2 f0 = __half22float2(v0);
    float2 f1 = __half22float2(v1);
    float2 f2 = __half22float2(v2);
    float2 f3 = __half22float2(v3);
    a0 += (f0.x + f1.x) + (f2.x + f3.x);
    a1 += (f0.y + f1.y) + (f2.y + f3.y);
  }
  for (; e < end; ++e) {
    int s0 = csr_src[e];
    float2 f0 = __half22float2(*(const __half2*)(h + (size_t)s0 * 128 + lane * 2));
    a0 += f0.x;
    a1 += f0.y;
  }
  float w = inv_deg[gw];
  __half2 r;
  r.x = __float2half(a0 * w);
  r.y = __float2half(a1 * w);
  *(__half2*)(agg + (size_t)gw * 128 + lane * 2) = r;
}

// out[m][n] = relu( h[m]@Ws + agg[m]@Wn + b ), K=256 via mfma_f32_16x16x32_f16.
// Block = 256 threads = 4 waves; wave w does rows [blk*64+w*16, +16), all 128 cols.
__global__ __launch_bounds__(256) void k_linear_mfma(
    const __half* __restrict__ h, const __half* __restrict__ agg,
    const __half* __restrict__ Wt, const float* __restrict__ bias,
    __half* __restrict__ out, int n_nodes) {
  int tid = threadIdx.x;
  int wave = tid >> 6;
  int lane = tid & 63;
  int m0 = blockIdx.x * 64 + wave * 16;
  int lr = lane & 15;
  int lg = lane >> 4;
  f32x4 acc[8];
#pragma unroll
  for (int ct = 0; ct < 8; ++ct) acc[ct] = (f32x4){0.f, 0.f, 0.f, 0.f};

  int arow = m0 + lr;
  if (arow >= n_nodes) arow = n_nodes - 1;
  const __half* hrow = h + (size_t)arow * 128;
  const __half* grow = agg + (size_t)arow * 128;

#pragma unroll
  for (int ks = 0; ks < 8; ++ks) {
    const __half* srcp = (ks < 4) ? hrow : grow;
    int koff = (ks & 3) * 32 + lg * 8;
    f16x8 a = *(const f16x8*)(srcp + koff);
    int kb = ks * 32 + lg * 8;
#pragma unroll
    for (int ct = 0; ct < 8; ++ct) {
      f16x8 b = *(const f16x8*)(Wt + (size_t)(ct * 16 + lr) * 256 + kb);
      acc[ct] = __builtin_amdgcn_mfma_f32_16x16x32_f16(a, b, acc[ct], 0, 0, 0);
    }
  }

#pragma unroll
  for (int ct = 0; ct < 8; ++ct) {
    int n_col = ct * 16 + lr;
    float bv = bias[n_col];
#pragma unroll
    for (int r = 0; r < 4; ++r) {
      int m = m0 + lg * 4 + r;
      if (m < n_nodes)
        out[(size_t)m * 128 + n_col] = __float2half(fmaxf(acc[ct][r] + bv, 0.f));
    }
  }
}

// 256 blocks x 256 threads; wave w handles rows blk*4+w (stride 1024), lane owns
// 2 dims via half2; LDS reduce across the 4 waves -> partial[blk][128].
__global__ __launch_bounds__(256) void k_pool(const __half* __restrict__ h,
                                              float* __restrict__ partial, int n_nodes) {
  __shared__ float red[4][128];
  int tid = threadIdx.x;
  int lane = tid & 63;
  int w = tid >> 6;
  float a0 = 0.f, a1 = 0.f;
  for (int n = blockIdx.x * 4 + w; n < n_nodes; n += gridDim.x * 4) {
    float2 f = __half22float2(*(const __half2*)(h + (size_t)n * 128 + lane * 2));
    a0 += f.x;
    a1 += f.y;
  }
  red[w][lane * 2] = a0;
  red[w][lane * 2 + 1] = a1;
  __syncthreads();
  if (tid < 128) {
    partial[(size_t)blockIdx.x * 128 + tid] =
        (red[0][tid] + red[1][tid]) + (red[2][tid] + red[3][tid]);
  }
}

// 512 threads: chunked parallel reduce of partial[256][128] -> g[128], then
// chunked classifier dot g@Wc[128][64] + bc. Max serial chain: 64 loads.
__global__ __launch_bounds__(512) void k_final(const float* __restrict__ partial,
                                               const float* __restrict__ Wc,
                                               const float* __restrict__ bc,
                                               float* __restrict__ out, int n_nodes) {
  __shared__ float red[4][128];
  __shared__ float gs[128];
  __shared__ float red2[8][64];
  int tid = threadIdx.x;
  int j = tid & 127;
  int c = tid >> 7;  // 4 chunks of 64 partials
  float s = 0.f;
#pragma unroll
  for (int b = 0; b < 64; ++b) s += partial[(size_t)(c * 64 + b) * 128 + j];
  red[c][j] = s;
  __syncthreads();
  if (tid < 128) {
    float g = (red[0][tid] + red[1][tid]) + (red[2][tid] + red[3][tid]);
    gs[tid] = g / (float)n_nodes;
  }
  __syncthreads();
  {
    int jo = tid & 63;
    int c2 = tid >> 6;  // 8 chunks of 16 k
    float s2 = 0.f;
#pragma unroll
    for (int d = 0; d < 16; ++d)
      s2 += gs[c2 * 16 + d] * Wc[(size_t)(c2 * 16 + d) * 64 + jo];
    red2[c2][jo] = s2;
  }
  __syncthreads();
  if (tid < 64) {
    float o = bc[tid];
#pragma unroll
    for (int c2 = 0; c2 < 8; ++c2) o += red2[c2][tid];
    out[tid] = o;
  }
}

extern "C" void kernel_launch(void* const* d_in, const int* in_sizes, int n_in,
                              void* d_out, int out_size, void* d_ws, size_t ws_size,
                              hipStream_t stream) {
  const float* x = (const float*)d_in[0];
  const int* ei = (const int*)d_in[1];
  const float* Ws11 = (const float*)d_in[2];
  const float* Wn11 = (const float*)d_in[3];
  const float* b11 = (const float*)d_in[4];
  const float* Ws12 = (const float*)d_in[5];
  const float* Wn12 = (const float*)d_in[6];
  const float* b12 = (const float*)d_in[7];
  const float* Ws21 = (const float*)d_in[8];
  const float* Wn21 = (const float*)d_in[9];
  const float* b21 = (const float*)d_in[10];
  const float* Ws22 = (const float*)d_in[11];
  const float* Wn22 = (const float*)d_in[12];
  const float* b22 = (const float*)d_in[13];
  const float* Wc = (const float*)d_in[14];
  const float* bc = (const float*)d_in[15];

  int N = in_sizes[0] / 128;
  int E = in_sizes[1] / 2;
  const int* src = ei;
  const int* tgt = ei + E;

  // workspace layout (256B-aligned chunks)
  char* w = (char*)d_ws;
  size_t off = 0;
  auto alloc = [&](size_t bytes) {
    void* p = w + off;
    off += (bytes + 255) & ~(size_t)255;
    return p;
  };
  __half* xh = (__half*)alloc((size_t)N * 128 * 2);
  __half* hA = (__half*)alloc((size_t)N * 128 * 2);
  __half* hB = (__half*)alloc((size_t)N * 128 * 2);
  __half* aggb = (__half*)alloc((size_t)N * 128 * 2);
  __half* Wt = (__half*)alloc((size_t)4 * 32768 * 2);
  float* partial = (float*)alloc((size_t)256 * 128 * 4);
  float* inv_deg = (float*)alloc((size_t)N * 4);
  int* deg = (int*)alloc((size_t)N * 4);
  int* row_start = (int*)alloc((size_t)(N + 1) * 4);
  int* cursor = (int*)alloc((size_t)N * 4);
  int* csr_src = (int*)alloc((size_t)E * 4);
  int* scanp = (int*)alloc((size_t)N * 4);
  int* blocksum = (int*)alloc((size_t)256 * 4);

  hipMemsetAsync(deg, 0, (size_t)N * 4, stream);
  hipMemsetAsync(partial, 0, (size_t)256 * 128 * 4, stream);
  int eb = (E + 255) / 256;
  int nb = (N + 255) / 256;
  k_deg<<<eb, 256, 0, stream>>>(tgt, deg, E);
  k_scan1<<<nb, 256, 0, stream>>>(deg, scanp, blocksum, inv_deg, N);
  k_scan2<<<1, 256, 0, stream>>>(blocksum, nb);
  k_scan3<<<nb, 256, 0, stream>>>(scanp, blocksum, row_start, cursor, N, E);
  k_scatter<<<eb, 256, 0, stream>>>(src, tgt, cursor, csr_src, E);

  int total8 = N * 128 / 8;
  k_cvt_x<<<(total8 + 255) / 256, 256, 0, stream>>>(x, xh, total8);
  WPack wp;
  wp.s[0] = Ws11; wp.s[1] = Ws12; wp.s[2] = Ws21; wp.s[3] = Ws22;
  wp.n[0] = Wn11; wp.n[1] = Wn12; wp.n[2] = Wn21; wp.n[3] = Wn22;
  k_prep_w<<<dim3(128, 4), 256, 0, stream>>>(wp, Wt);

  int ab = (N + 3) / 4;     // k_agg_h: 4 waves/block, 1 node/wave
  int lb = (N + 63) / 64;   // k_linear_mfma: 64 rows/block

  // layer 1: xh -> hA
  k_agg_h<<<ab, 256, 0, stream>>>(xh, csr_src, row_start, inv_deg, aggb, N);
  k_linear_mfma<<<lb, 256, 0, stream>>>(xh, aggb, Wt + 0 * 32768, b11, hA, N);
  // layer 2: hA -> hB
  k_agg_h<<<ab, 256, 0, stream>>>(hA, csr_src, row_start, inv_deg, aggb, N);
  k_linear_mfma<<<lb, 256, 0, stream>>>(hA, aggb, Wt + 1 * 32768, b12, hB, N);
  // layer 3: hB -> hA
  k_agg_h<<<ab, 256, 0, stream>>>(hB, csr_src, row_start, inv_deg, aggb, N);
  k_linear_mfma<<<lb, 256, 0, stream>>>(hB, aggb, Wt + 2 * 32768, b21, hA, N);
  // layer 4: hA -> hB
  k_agg_h<<<ab, 256, 0, stream>>>(hA, csr_src, row_start, inv_deg, aggb, N);
  k_linear_mfma<<<lb, 256, 0, stream>>>(hA, aggb, Wt + 3 * 32768, b22, hB, N);

  k_pool<<<256, 256, 0, stream>>>(hB, partial, N);
  k_final<<<1, 512, 0, stream>>>(partial, Wc, bc, (float*)d_out, N);
}